// Round 1
// baseline (1875.797 us; speedup 1.0000x reference)
//
#include <hip/hip_runtime.h>
#include <math.h>

#define EPSF 1e-7f
#define MAXNRM 10.0f

__device__ __forceinline__ float wsum(float v) {
    #pragma unroll
    for (int off = 32; off > 0; off >>= 1) v += __shfl_xor(v, off, 64);
    return v;
}

// ---------------- logmap0 of embeddings -> t ----------------
__global__ void k_logmap(const float* __restrict__ eu, const float* __restrict__ ei,
                         int Nu, int Ntot, float* __restrict__ out) {
    int idx = blockIdx.x * blockDim.x + threadIdx.x;
    if (idx >= Ntot * 64) return;
    int n = idx >> 6, d = idx & 63;
    const float* src = (n < Nu) ? (eu + (size_t)n * 64) : (ei + (size_t)(n - Nu) * 64);
    float x0 = src[0];
    float alpha = fmaxf(x0, 1.0f + EPSF);
    float coef = acoshf(alpha) / sqrtf(fmaxf(alpha * alpha - 1.0f, EPSF));
    out[idx] = (d == 0) ? 0.0f : coef * src[d];
}

// ---------------- MoE: Y = sum_e softmax(X@GW+GB)_e * (X@W[e] + B[e]) ----------------
__global__ __launch_bounds__(256) void k_moe(
    const float* __restrict__ X, float* __restrict__ Y,
    const float* __restrict__ W, const float* __restrict__ Bb,
    const float* __restrict__ GW, const float* __restrict__ GB)
{
    __shared__ float sX[32][68];
    __shared__ float sG[32][8];
    const int tid = threadIdx.x;
    const int n0 = blockIdx.x * 32;

    for (int i = tid; i < 2048; i += 256)
        sX[i >> 6][i & 63] = X[(size_t)n0 * 64 + i];
    __syncthreads();

    {
        const int n = tid >> 3, e = tid & 7;
        float lg = GB[e];
        #pragma unroll 16
        for (int d = 0; d < 64; ++d) lg += sX[n][d] * GW[d * 8 + e];
        sG[n][e] = lg;
    }
    __syncthreads();
    if (tid < 32) {
        float mx = -1e30f;
        #pragma unroll
        for (int e = 0; e < 8; ++e) mx = fmaxf(mx, sG[tid][e]);
        float ex[8]; float s = 0.f;
        #pragma unroll
        for (int e = 0; e < 8; ++e) { ex[e] = expf(sG[tid][e] - mx); s += ex[e]; }
        float inv = 1.0f / s;
        #pragma unroll
        for (int e = 0; e < 8; ++e) sG[tid][e] = ex[e] * inv;
    }
    __syncthreads();

    const int o = tid & 63, nq = tid >> 6;
    float y[8][8];
    #pragma unroll
    for (int k = 0; k < 8; ++k)
        #pragma unroll
        for (int e = 0; e < 8; ++e) y[k][e] = 0.f;

    for (int dc = 0; dc < 16; ++dc) {
        float a[8][4];
        #pragma unroll
        for (int k = 0; k < 8; ++k) {
            float4 av = *(const float4*)(&sX[nq + 4 * k][dc * 4]);
            a[k][0] = av.x; a[k][1] = av.y; a[k][2] = av.z; a[k][3] = av.w;
        }
        #pragma unroll
        for (int e = 0; e < 8; ++e) {
            #pragma unroll
            for (int j = 0; j < 4; ++j) {
                const float w = W[(((size_t)e) << 12) + (size_t)(dc * 4 + j) * 64 + o];
                #pragma unroll
                for (int k = 0; k < 8; ++k) y[k][e] += a[k][j] * w;
            }
        }
    }

    #pragma unroll
    for (int k = 0; k < 8; ++k) {
        const int n = nq + 4 * k;
        float acc = 0.f;
        #pragma unroll
        for (int e = 0; e < 8; ++e) acc += sG[n][e] * (y[k][e] + Bb[e * 64 + o]);
        Y[(size_t)(n0 + n) * 64 + o] = acc;
    }
}

// ---------------- VAE mid: mu/logvar, kl partial, u=mu+eps*std, h=logmap0(expmap0(u,proj)) ----------------
__global__ __launch_bounds__(256) void k_vae(
    const float* __restrict__ M, float* __restrict__ Hout,
    const float* __restrict__ EPSN,
    const float* __restrict__ muW, const float* __restrict__ mub,
    const float* __restrict__ lvW, const float* __restrict__ lvb,
    float* __restrict__ klslot)
{
    __shared__ float sM[32][68];
    __shared__ float sC[32];
    const int tid = threadIdx.x;
    const int n0 = blockIdx.x * 32;

    for (int i = tid; i < 2048; i += 256)
        sM[i >> 6][i & 63] = M[(size_t)n0 * 64 + i];
    __syncthreads();

    const int o = tid & 63, nq = tid >> 6;
    float ymu[8], ylv[8];
    #pragma unroll
    for (int k = 0; k < 8; ++k) { ymu[k] = 0.f; ylv[k] = 0.f; }

    for (int dc = 0; dc < 16; ++dc) {
        float a[8][4];
        #pragma unroll
        for (int k = 0; k < 8; ++k) {
            float4 av = *(const float4*)(&sM[nq + 4 * k][dc * 4]);
            a[k][0] = av.x; a[k][1] = av.y; a[k][2] = av.z; a[k][3] = av.w;
        }
        #pragma unroll
        for (int j = 0; j < 4; ++j) {
            const float wm = muW[(size_t)(dc * 4 + j) * 64 + o];
            const float wl = lvW[(size_t)(dc * 4 + j) * 64 + o];
            #pragma unroll
            for (int k = 0; k < 8; ++k) { ymu[k] += a[k][j] * wm; ylv[k] += a[k][j] * wl; }
        }
    }

    float u[8];
    float klp = 0.f;
    #pragma unroll
    for (int k = 0; k < 8; ++k) {
        const int n = nq + 4 * k;
        const float mu = ymu[k] + mub[o];
        const float lv = ylv[k] + lvb[o];
        const float elv = expf(lv);
        klp += 1.0f + lv - mu * mu - elv;
        u[k] = mu + EPSN[(size_t)(n0 + n) * 64 + o] * expf(0.5f * lv);
    }
    klp = wsum(klp);
    if ((tid & 63) == 0) atomicAdd(&klslot[(blockIdx.x * 4 + nq) & 255], klp);

    __syncthreads();   // all reads of sM (dc loop) done
    #pragma unroll
    for (int k = 0; k < 8; ++k) sM[nq + 4 * k][o] = u[k];
    __syncthreads();

    if (tid < 32) {
        float ss = 0.f;
        for (int d = 1; d < 64; ++d) ss += sM[tid][d] * sM[tid][d];
        const float nr = fmaxf(sqrtf(ss), EPSF);
        const float r = sinhf(nr) / nr;
        const float sn = r * sqrtf(ss);
        const float scale = fminf(1.0f, MAXNRM / fmaxf(sn, EPSF));
        const float mult = r * scale;
        const float s2 = mult * mult * ss;
        const float z0 = sqrtf(1.0f + s2);
        const float alpha = fmaxf(z0, 1.0f + EPSF);
        const float coef = acoshf(alpha) / sqrtf(fmaxf(alpha * alpha - 1.0f, EPSF));
        sC[tid] = coef * mult;
    }
    __syncthreads();

    #pragma unroll
    for (int k = 0; k < 8; ++k) {
        const int n = nq + 4 * k;
        Hout[(size_t)(n0 + n) * 64 + o] = (o == 0) ? 0.f : sC[n] * sM[n][o];
    }
}

// ---------------- FFN: h -> relu(h@f1W+f1b) -> @f2W+f2b (in-place rows) ----------------
__global__ __launch_bounds__(256) void k_ffn(
    float* __restrict__ Hio,
    const float* __restrict__ f1W, const float* __restrict__ f1b,
    const float* __restrict__ f2W, const float* __restrict__ f2b)
{
    __shared__ float sH[32][68];
    __shared__ float sH1[32][132];
    const int tid = threadIdx.x;
    const int n0 = blockIdx.x * 32;

    for (int i = tid; i < 2048; i += 256)
        sH[i >> 6][i & 63] = Hio[(size_t)n0 * 64 + i];
    __syncthreads();

    const int o = tid & 63, nq = tid >> 6;
    float y0[8], y1[8];
    #pragma unroll
    for (int k = 0; k < 8; ++k) { y0[k] = 0.f; y1[k] = 0.f; }

    for (int dc = 0; dc < 16; ++dc) {
        float a[8][4];
        #pragma unroll
        for (int k = 0; k < 8; ++k) {
            float4 av = *(const float4*)(&sH[nq + 4 * k][dc * 4]);
            a[k][0] = av.x; a[k][1] = av.y; a[k][2] = av.z; a[k][3] = av.w;
        }
        #pragma unroll
        for (int j = 0; j < 4; ++j) {
            const float w0 = f1W[(size_t)(dc * 4 + j) * 128 + o];
            const float w1 = f1W[(size_t)(dc * 4 + j) * 128 + 64 + o];
            #pragma unroll
            for (int k = 0; k < 8; ++k) { y0[k] += a[k][j] * w0; y1[k] += a[k][j] * w1; }
        }
    }
    #pragma unroll
    for (int k = 0; k < 8; ++k) {
        const int n = nq + 4 * k;
        sH1[n][o] = fmaxf(y0[k] + f1b[o], 0.f);
        sH1[n][64 + o] = fmaxf(y1[k] + f1b[64 + o], 0.f);
    }
    __syncthreads();

    float y2[8];
    #pragma unroll
    for (int k = 0; k < 8; ++k) y2[k] = 0.f;
    for (int dc = 0; dc < 32; ++dc) {
        float a[8][4];
        #pragma unroll
        for (int k = 0; k < 8; ++k) {
            float4 av = *(const float4*)(&sH1[nq + 4 * k][dc * 4]);
            a[k][0] = av.x; a[k][1] = av.y; a[k][2] = av.z; a[k][3] = av.w;
        }
        #pragma unroll
        for (int j = 0; j < 4; ++j) {
            const float w = f2W[(size_t)(dc * 4 + j) * 64 + o];
            #pragma unroll
            for (int k = 0; k < 8; ++k) y2[k] += a[k][j] * w;
        }
    }
    #pragma unroll
    for (int k = 0; k < 8; ++k)
        Hio[(size_t)(n0 + nq + 4 * k) * 64 + o] = y2[k] + f2b[o];
}

// ---------------- recon loss: mean sqdist(expmap0(hm,proj), expmap0(m)) ----------------
__global__ void k_recon(const float* __restrict__ HM, const float* __restrict__ M,
                        int Ntot, float* __restrict__ slot)
{
    const int w = threadIdx.x >> 6, d = threadIdx.x & 63;
    const int n = blockIdx.x * 4 + w;
    if (n >= Ntot) return;
    const float hv = HM[(size_t)n * 64 + d];
    const float mv = M[(size_t)n * 64 + d];
    const float ssh = wsum(d == 0 ? 0.f : hv * hv);
    const float ssm = wsum(d == 0 ? 0.f : mv * mv);

    const float nm = fmaxf(sqrtf(ssm), EPSF);
    const float rm = sinhf(nm) / nm;
    const float em = (d == 0) ? coshf(nm) : rm * mv;

    const float nh = fmaxf(sqrtf(ssh), EPSF);
    const float rh = sinhf(nh) / nh;
    const float sn = rh * sqrtf(ssh);
    const float scale = fminf(1.0f, MAXNRM / fmaxf(sn, EPSF));
    const float mult = rh * scale;
    const float rec = (d == 0) ? sqrtf(1.0f + mult * mult * ssh) : mult * hv;

    const float inner = wsum(d == 0 ? -rec * em : rec * em);
    if (d == 0) {
        const float dd = acoshf(fmaxf(-inner, 1.0f + EPSF));
        atomicAdd(&slot[(blockIdx.x * 4 + w) & 255], dd * dd);
    }
}

// ---------------- CSR build ----------------
__global__ void k_count(const int* __restrict__ rows, int nnz, int* __restrict__ cnt) {
    int i = blockIdx.x * blockDim.x + threadIdx.x;
    if (i < nnz) atomicAdd(&cnt[rows[i]], 1);
}

__global__ __launch_bounds__(1024) void k_scan1(const int* __restrict__ cnt, int n,
                                                int* __restrict__ F, int* __restrict__ bsum) {
    __shared__ int s[1024];
    const int tid = threadIdx.x;
    const int i = blockIdx.x * 1024 + tid;
    int v = (i < n) ? cnt[i] : 0;
    s[tid] = v;
    __syncthreads();
    for (int off = 1; off < 1024; off <<= 1) {
        int t = (tid >= off) ? s[tid - off] : 0;
        __syncthreads();
        s[tid] += t;
        __syncthreads();
    }
    if (i < n) F[i] = s[tid] - v;
    if (tid == 1023) bsum[blockIdx.x] = s[tid];
}

__global__ void k_scan2(int* __restrict__ bsum, int nb, int* __restrict__ F, int Ntot, int nnz) {
    if (threadIdx.x == 0 && blockIdx.x == 0) {
        int run = 0;
        for (int b = 0; b < nb; ++b) { int t = bsum[b]; bsum[b] = run; run += t; }
        F[Ntot] = nnz;
    }
}

__global__ __launch_bounds__(1024) void k_scan3(int* __restrict__ F, const int* __restrict__ bsum,
                                                int n, int* __restrict__ cur) {
    int i = blockIdx.x * 1024 + threadIdx.x;
    if (i < n) { int v = F[i] + bsum[blockIdx.x]; F[i] = v; cur[i] = v; }
}

__global__ void k_scatter(const int* __restrict__ rows, const int* __restrict__ cols,
                          const float* __restrict__ vals, int nnz,
                          int* __restrict__ cur, int* __restrict__ scol, float* __restrict__ sval) {
    int i = blockIdx.x * blockDim.x + threadIdx.x;
    if (i < nnz) {
        int pos = atomicAdd(&cur[rows[i]], 1);
        scol[pos] = cols[i];
        sval[pos] = vals[i];
    }
}

// ---------------- SpMM gather: out[r] = sum val*in[col]; osum accumulate ----------------
template <int MODE>
__global__ void k_spmm(const float* __restrict__ in, float* __restrict__ out,
                       float* __restrict__ osum,
                       const int* __restrict__ rs, const int* __restrict__ scol,
                       const float* __restrict__ sval, int Ntot)
{
    const int w = threadIdx.x >> 6, d = threadIdx.x & 63;
    const int r = blockIdx.x * 4 + w;
    if (r >= Ntot) return;
    const int e0 = rs[r], e1 = rs[r + 1];
    float acc0 = 0.f, acc1 = 0.f;
    int e = e0;
    for (; e + 2 <= e1; e += 2) {
        const int c0 = scol[e], c1 = scol[e + 1];
        const float v0 = sval[e], v1 = sval[e + 1];
        acc0 += v0 * in[((size_t)c0 << 6) + d];
        acc1 += v1 * in[((size_t)c1 << 6) + d];
    }
    if (e < e1) acc0 += sval[e] * in[((size_t)scol[e] << 6) + d];
    const float acc = acc0 + acc1;
    const size_t oi = ((size_t)r << 6) + d;
    out[oi] = acc;
    if (MODE == 0) osum[oi] = acc; else osum[oi] += acc;
}

// ---------------- expmap0(out_sum, project=True) ----------------
__global__ void k_expmap_proj(const float* __restrict__ in, float* __restrict__ out, int Ntot) {
    const int w = threadIdx.x >> 6, d = threadIdx.x & 63;
    const int n = blockIdx.x * 4 + w;
    if (n >= Ntot) return;
    const float v = in[((size_t)n << 6) + d];
    const float ss = wsum(d == 0 ? 0.f : v * v);
    const float nr = fmaxf(sqrtf(ss), EPSF);
    const float r = sinhf(nr) / nr;
    const float sn = r * sqrtf(ss);
    const float scale = fminf(1.0f, MAXNRM / fmaxf(sn, EPSF));
    const float mult = r * scale;
    out[((size_t)n << 6) + d] = (d == 0) ? sqrtf(1.0f + mult * mult * ss) : mult * v;
}

// ---------------- triple margin loss ----------------
__global__ void k_triples(const float* __restrict__ O, const int* __restrict__ tri,
                          int T, float* __restrict__ slot)
{
    const int w = threadIdx.x >> 6, d = threadIdx.x & 63;
    const int t = blockIdx.x * 4 + w;
    if (t >= T) return;
    const int a = tri[t * 3], p = tri[t * 3 + 1], nn = tri[t * 3 + 2];
    const float av = O[((size_t)a << 6) + d];
    const float pv = O[((size_t)p << 6) + d];
    const float nv = O[((size_t)nn << 6) + d];
    const float sgn = (d == 0) ? -1.f : 1.f;
    const float i1 = wsum(sgn * av * pv);
    const float i2 = wsum(sgn * av * nv);
    if (d == 0) {
        const float d1 = acoshf(fmaxf(-i1, 1.0f + EPSF));
        const float d2 = acoshf(fmaxf(-i2, 1.0f + EPSF));
        const float l = d1 * d1 - d2 * d2 + 0.1f;
        if (l > 0.f) atomicAdd(&slot[t & 255], l);
    }
}

// ---------------- finalize ----------------
__global__ void k_final(const float* __restrict__ slots, float* __restrict__ out, int Ntot)
{
    const int tid = threadIdx.x;
    float m = slots[tid], r = slots[256 + tid], k = slots[512 + tid];
    m = wsum(m); r = wsum(r); k = wsum(k);
    __shared__ float sm[4], sr[4], sk[4];
    if ((tid & 63) == 0) { sm[tid >> 6] = m; sr[tid >> 6] = r; sk[tid >> 6] = k; }
    __syncthreads();
    if (tid == 0) {
        const float M = sm[0] + sm[1] + sm[2] + sm[3];
        const float R = sr[0] + sr[1] + sr[2] + sr[3];
        const float K = sk[0] + sk[1] + sk[2] + sk[3];
        const float recon = R / (float)Ntot;
        const float kl = -0.5f * K / ((float)Ntot * 64.0f);
        out[0] = M + 0.1f * (recon + kl);
    }
}

extern "C" void kernel_launch(void* const* d_in, const int* in_sizes, int n_in,
                              void* d_out, int out_size, void* d_ws, size_t ws_size,
                              hipStream_t stream)
{
    const float* emb_user = (const float*)d_in[0];
    const float* emb_item = (const float*)d_in[1];
    const int*   adj_rows = (const int*)d_in[2];
    const int*   adj_cols = (const int*)d_in[3];
    const float* adj_vals = (const float*)d_in[4];
    const int*   triples  = (const int*)d_in[5];
    const float* epsin    = (const float*)d_in[6];
    const float* tW  = (const float*)d_in[7];
    const float* tb  = (const float*)d_in[8];
    const float* tgW = (const float*)d_in[9];
    const float* tgb = (const float*)d_in[10];
    const float* muW = (const float*)d_in[11];
    const float* mub = (const float*)d_in[12];
    const float* lvW = (const float*)d_in[13];
    const float* lvb = (const float*)d_in[14];
    const float* f1W = (const float*)d_in[15];
    const float* f1b = (const float*)d_in[16];
    const float* f2W = (const float*)d_in[17];
    const float* f2b = (const float*)d_in[18];
    const float* dW  = (const float*)d_in[19];
    const float* db  = (const float*)d_in[20];
    const float* dgW = (const float*)d_in[21];
    const float* dgb = (const float*)d_in[22];

    const int Nu = in_sizes[0] / 64, Ni = in_sizes[1] / 64;
    const int N = Nu + Ni;            // 100000
    const int NNZ = in_sizes[4];      // 3200000
    const int T = in_sizes[5] / 3;    // 262144

    float* ws = (float*)d_ws;
    size_t off = 0;
    float* slots = ws + off; off += 1024;            // [0..256) margin, [256..512) recon, [512..768) kl
    float* A  = ws + off; off += (size_t)N * 64;     // t / h / h2 ; later overlaid with CSR cols/vals
    float* B  = ws + off; off += (size_t)N * 64;     // m
    float* C  = ws + off; off += (size_t)N * 64;     // hm, then out_sum
    float* Dd = ws + off; off += (size_t)N * 64;     // spmm ping
    float* Ee = ws + off; off += (size_t)N * 64;     // spmm pong, then out
    int*   F  = (int*)(ws + off); off += (size_t)N + 64;   // row_start (N+1)
    int*   G  = (int*)(ws + off); off += (size_t)N;        // counts / cursor
    int*   bsum = (int*)(ws + off); off += 1024;

    // CSR storage overlays A (A is dead after second k_moe, which precedes k_scatter)
    int*   Hc = (int*)A;               // sorted cols [NNZ]
    float* Iv = A + (size_t)NNZ;       // sorted vals [NNZ]  (2*NNZ <= N*64)

    hipMemsetAsync(slots, 0, 1024 * sizeof(float), stream);
    hipMemsetAsync(G, 0, (size_t)N * sizeof(int), stream);

    const int nb32 = N / 32;          // 3125
    const int nbN4 = (N + 3) / 4;     // 25000

    k_logmap<<<(N * 64 + 255) / 256, 256, 0, stream>>>(emb_user, emb_item, Nu, N, A);
    k_moe<<<nb32, 256, 0, stream>>>(A, B, tW, tb, tgW, tgb);
    k_vae<<<nb32, 256, 0, stream>>>(B, A, epsin, muW, mub, lvW, lvb, slots + 512);
    k_ffn<<<nb32, 256, 0, stream>>>(A, f1W, f1b, f2W, f2b);
    k_moe<<<nb32, 256, 0, stream>>>(A, C, dW, db, dgW, dgb);
    k_recon<<<nbN4, 256, 0, stream>>>(C, B, N, slots + 256);

    k_count<<<(NNZ + 255) / 256, 256, 0, stream>>>(adj_rows, NNZ, G);
    const int nsb = (N + 1023) / 1024;   // 98
    k_scan1<<<nsb, 1024, 0, stream>>>(G, N, F, bsum);
    k_scan2<<<1, 64, 0, stream>>>(bsum, nsb, F, N, NNZ);
    k_scan3<<<nsb, 1024, 0, stream>>>(F, bsum, N, G);
    k_scatter<<<(NNZ + 255) / 256, 256, 0, stream>>>(adj_rows, adj_cols, adj_vals, NNZ, G, Hc, Iv);

    k_spmm<0><<<nbN4, 256, 0, stream>>>(B,  Dd, C, F, Hc, Iv, N);
    k_spmm<1><<<nbN4, 256, 0, stream>>>(Dd, Ee, C, F, Hc, Iv, N);
    k_spmm<1><<<nbN4, 256, 0, stream>>>(Ee, Dd, C, F, Hc, Iv, N);

    k_expmap_proj<<<nbN4, 256, 0, stream>>>(C, Ee, N);
    k_triples<<<(T + 3) / 4, 256, 0, stream>>>(Ee, triples, T, slots);
    k_final<<<1, 256, 0, stream>>>(slots, (float*)d_out, N);
}

// Round 2
// 1329.241 us; speedup vs baseline: 1.4112x; 1.4112x over previous
//
#include <hip/hip_runtime.h>
#include <math.h>

#define EPSF 1e-7f
#define MAXNRM 10.0f

__device__ __forceinline__ float wsum(float v) {
    #pragma unroll
    for (int off = 32; off > 0; off >>= 1) v += __shfl_xor(v, off, 64);
    return v;
}

// ---------------- logmap0 of embeddings -> t ----------------
__global__ void k_logmap(const float* __restrict__ eu, const float* __restrict__ ei,
                         int Nu, int Ntot, float* __restrict__ out) {
    int idx = blockIdx.x * blockDim.x + threadIdx.x;
    if (idx >= Ntot * 64) return;
    int n = idx >> 6, d = idx & 63;
    const float* src = (n < Nu) ? (eu + (size_t)n * 64) : (ei + (size_t)(n - Nu) * 64);
    float x0 = src[0];
    float alpha = fmaxf(x0, 1.0f + EPSF);
    float coef = acoshf(alpha) / sqrtf(fmaxf(alpha * alpha - 1.0f, EPSF));
    out[idx] = (d == 0) ? 0.0f : coef * src[d];
}

// ---------------- MoE: Y = sum_e softmax(X@GW+GB)_e * (X@W[e] + B[e]) ----------------
__global__ __launch_bounds__(256) void k_moe(
    const float* __restrict__ X, float* __restrict__ Y,
    const float* __restrict__ W, const float* __restrict__ Bb,
    const float* __restrict__ GW, const float* __restrict__ GB)
{
    __shared__ float sX[32][68];
    __shared__ float sG[32][8];
    const int tid = threadIdx.x;
    const int n0 = blockIdx.x * 32;

    for (int i = tid; i < 2048; i += 256)
        sX[i >> 6][i & 63] = X[(size_t)n0 * 64 + i];
    __syncthreads();

    {
        const int n = tid >> 3, e = tid & 7;
        float lg = GB[e];
        #pragma unroll 16
        for (int d = 0; d < 64; ++d) lg += sX[n][d] * GW[d * 8 + e];
        sG[n][e] = lg;
    }
    __syncthreads();
    if (tid < 32) {
        float mx = -1e30f;
        #pragma unroll
        for (int e = 0; e < 8; ++e) mx = fmaxf(mx, sG[tid][e]);
        float ex[8]; float s = 0.f;
        #pragma unroll
        for (int e = 0; e < 8; ++e) { ex[e] = expf(sG[tid][e] - mx); s += ex[e]; }
        float inv = 1.0f / s;
        #pragma unroll
        for (int e = 0; e < 8; ++e) sG[tid][e] = ex[e] * inv;
    }
    __syncthreads();

    const int o = tid & 63, nq = tid >> 6;
    float y[8][8];
    #pragma unroll
    for (int k = 0; k < 8; ++k)
        #pragma unroll
        for (int e = 0; e < 8; ++e) y[k][e] = 0.f;

    for (int dc = 0; dc < 16; ++dc) {
        float a[8][4];
        #pragma unroll
        for (int k = 0; k < 8; ++k) {
            float4 av = *(const float4*)(&sX[nq + 4 * k][dc * 4]);
            a[k][0] = av.x; a[k][1] = av.y; a[k][2] = av.z; a[k][3] = av.w;
        }
        #pragma unroll
        for (int e = 0; e < 8; ++e) {
            #pragma unroll
            for (int j = 0; j < 4; ++j) {
                const float w = W[(((size_t)e) << 12) + (size_t)(dc * 4 + j) * 64 + o];
                #pragma unroll
                for (int k = 0; k < 8; ++k) y[k][e] += a[k][j] * w;
            }
        }
    }

    #pragma unroll
    for (int k = 0; k < 8; ++k) {
        const int n = nq + 4 * k;
        float acc = 0.f;
        #pragma unroll
        for (int e = 0; e < 8; ++e) acc += sG[n][e] * (y[k][e] + Bb[e * 64 + o]);
        Y[(size_t)(n0 + n) * 64 + o] = acc;
    }
}

// ---------------- VAE mid ----------------
__global__ __launch_bounds__(256) void k_vae(
    const float* __restrict__ M, float* __restrict__ Hout,
    const float* __restrict__ EPSN,
    const float* __restrict__ muW, const float* __restrict__ mub,
    const float* __restrict__ lvW, const float* __restrict__ lvb,
    float* __restrict__ klslot)
{
    __shared__ float sM[32][68];
    __shared__ float sC[32];
    const int tid = threadIdx.x;
    const int n0 = blockIdx.x * 32;

    for (int i = tid; i < 2048; i += 256)
        sM[i >> 6][i & 63] = M[(size_t)n0 * 64 + i];
    __syncthreads();

    const int o = tid & 63, nq = tid >> 6;
    float ymu[8], ylv[8];
    #pragma unroll
    for (int k = 0; k < 8; ++k) { ymu[k] = 0.f; ylv[k] = 0.f; }

    for (int dc = 0; dc < 16; ++dc) {
        float a[8][4];
        #pragma unroll
        for (int k = 0; k < 8; ++k) {
            float4 av = *(const float4*)(&sM[nq + 4 * k][dc * 4]);
            a[k][0] = av.x; a[k][1] = av.y; a[k][2] = av.z; a[k][3] = av.w;
        }
        #pragma unroll
        for (int j = 0; j < 4; ++j) {
            const float wm = muW[(size_t)(dc * 4 + j) * 64 + o];
            const float wl = lvW[(size_t)(dc * 4 + j) * 64 + o];
            #pragma unroll
            for (int k = 0; k < 8; ++k) { ymu[k] += a[k][j] * wm; ylv[k] += a[k][j] * wl; }
        }
    }

    float u[8];
    float klp = 0.f;
    #pragma unroll
    for (int k = 0; k < 8; ++k) {
        const int n = nq + 4 * k;
        const float mu = ymu[k] + mub[o];
        const float lv = ylv[k] + lvb[o];
        const float elv = expf(lv);
        klp += 1.0f + lv - mu * mu - elv;
        u[k] = mu + EPSN[(size_t)(n0 + n) * 64 + o] * expf(0.5f * lv);
    }
    klp = wsum(klp);
    if ((tid & 63) == 0) atomicAdd(&klslot[(blockIdx.x * 4 + nq) & 255], klp);

    __syncthreads();
    #pragma unroll
    for (int k = 0; k < 8; ++k) sM[nq + 4 * k][o] = u[k];
    __syncthreads();

    if (tid < 32) {
        float ss = 0.f;
        for (int d = 1; d < 64; ++d) ss += sM[tid][d] * sM[tid][d];
        const float nr = fmaxf(sqrtf(ss), EPSF);
        const float r = sinhf(nr) / nr;
        const float sn = r * sqrtf(ss);
        const float scale = fminf(1.0f, MAXNRM / fmaxf(sn, EPSF));
        const float mult = r * scale;
        const float s2 = mult * mult * ss;
        const float z0 = sqrtf(1.0f + s2);
        const float alpha = fmaxf(z0, 1.0f + EPSF);
        const float coef = acoshf(alpha) / sqrtf(fmaxf(alpha * alpha - 1.0f, EPSF));
        sC[tid] = coef * mult;
    }
    __syncthreads();

    #pragma unroll
    for (int k = 0; k < 8; ++k) {
        const int n = nq + 4 * k;
        Hout[(size_t)(n0 + n) * 64 + o] = (o == 0) ? 0.f : sC[n] * sM[n][o];
    }
}

// ---------------- FFN ----------------
__global__ __launch_bounds__(256) void k_ffn(
    float* __restrict__ Hio,
    const float* __restrict__ f1W, const float* __restrict__ f1b,
    const float* __restrict__ f2W, const float* __restrict__ f2b)
{
    __shared__ float sH[32][68];
    __shared__ float sH1[32][132];
    const int tid = threadIdx.x;
    const int n0 = blockIdx.x * 32;

    for (int i = tid; i < 2048; i += 256)
        sH[i >> 6][i & 63] = Hio[(size_t)n0 * 64 + i];
    __syncthreads();

    const int o = tid & 63, nq = tid >> 6;
    float y0[8], y1[8];
    #pragma unroll
    for (int k = 0; k < 8; ++k) { y0[k] = 0.f; y1[k] = 0.f; }

    for (int dc = 0; dc < 16; ++dc) {
        float a[8][4];
        #pragma unroll
        for (int k = 0; k < 8; ++k) {
            float4 av = *(const float4*)(&sH[nq + 4 * k][dc * 4]);
            a[k][0] = av.x; a[k][1] = av.y; a[k][2] = av.z; a[k][3] = av.w;
        }
        #pragma unroll
        for (int j = 0; j < 4; ++j) {
            const float w0 = f1W[(size_t)(dc * 4 + j) * 128 + o];
            const float w1 = f1W[(size_t)(dc * 4 + j) * 128 + 64 + o];
            #pragma unroll
            for (int k = 0; k < 8; ++k) { y0[k] += a[k][j] * w0; y1[k] += a[k][j] * w1; }
        }
    }
    #pragma unroll
    for (int k = 0; k < 8; ++k) {
        const int n = nq + 4 * k;
        sH1[n][o] = fmaxf(y0[k] + f1b[o], 0.f);
        sH1[n][64 + o] = fmaxf(y1[k] + f1b[64 + o], 0.f);
    }
    __syncthreads();

    float y2[8];
    #pragma unroll
    for (int k = 0; k < 8; ++k) y2[k] = 0.f;
    for (int dc = 0; dc < 32; ++dc) {
        float a[8][4];
        #pragma unroll
        for (int k = 0; k < 8; ++k) {
            float4 av = *(const float4*)(&sH1[nq + 4 * k][dc * 4]);
            a[k][0] = av.x; a[k][1] = av.y; a[k][2] = av.z; a[k][3] = av.w;
        }
        #pragma unroll
        for (int j = 0; j < 4; ++j) {
            const float w = f2W[(size_t)(dc * 4 + j) * 64 + o];
            #pragma unroll
            for (int k = 0; k < 8; ++k) y2[k] += a[k][j] * w;
        }
    }
    #pragma unroll
    for (int k = 0; k < 8; ++k)
        Hio[(size_t)(n0 + nq + 4 * k) * 64 + o] = y2[k] + f2b[o];
}

// ---------------- recon loss ----------------
__global__ void k_recon(const float* __restrict__ HM, const float* __restrict__ M,
                        int Ntot, float* __restrict__ slot)
{
    const int w = threadIdx.x >> 6, d = threadIdx.x & 63;
    const int n = blockIdx.x * 4 + w;
    if (n >= Ntot) return;
    const float hv = HM[(size_t)n * 64 + d];
    const float mv = M[(size_t)n * 64 + d];
    const float ssh = wsum(d == 0 ? 0.f : hv * hv);
    const float ssm = wsum(d == 0 ? 0.f : mv * mv);

    const float nm = fmaxf(sqrtf(ssm), EPSF);
    const float rm = sinhf(nm) / nm;
    const float em = (d == 0) ? coshf(nm) : rm * mv;

    const float nh = fmaxf(sqrtf(ssh), EPSF);
    const float rh = sinhf(nh) / nh;
    const float sn = rh * sqrtf(ssh);
    const float scale = fminf(1.0f, MAXNRM / fmaxf(sn, EPSF));
    const float mult = rh * scale;
    const float rec = (d == 0) ? sqrtf(1.0f + mult * mult * ssh) : mult * hv;

    const float inner = wsum(d == 0 ? -rec * em : rec * em);
    if (d == 0) {
        const float dd = acoshf(fmaxf(-inner, 1.0f + EPSF));
        atomicAdd(&slot[(blockIdx.x * 4 + w) & 255], dd * dd);
    }
}

// ---------------- CSR build ----------------
__global__ void k_count(const int* __restrict__ rows, int nnz, int* __restrict__ cnt) {
    int i = blockIdx.x * blockDim.x + threadIdx.x;
    if (i < nnz) atomicAdd(&cnt[rows[i]], 1);
}

__global__ __launch_bounds__(1024) void k_scan1(const int* __restrict__ cnt, int n,
                                                int* __restrict__ F, int* __restrict__ bsum) {
    __shared__ int s[1024];
    const int tid = threadIdx.x;
    const int i = blockIdx.x * 1024 + tid;
    int v = (i < n) ? cnt[i] : 0;
    s[tid] = v;
    __syncthreads();
    for (int off = 1; off < 1024; off <<= 1) {
        int t = (tid >= off) ? s[tid - off] : 0;
        __syncthreads();
        s[tid] += t;
        __syncthreads();
    }
    if (i < n) F[i] = s[tid] - v;
    if (tid == 1023) bsum[blockIdx.x] = s[tid];
}

__global__ void k_scan2(int* __restrict__ bsum, int nb, int* __restrict__ F, int Ntot, int nnz) {
    if (threadIdx.x == 0 && blockIdx.x == 0) {
        int run = 0;
        for (int b = 0; b < nb; ++b) { int t = bsum[b]; bsum[b] = run; run += t; }
        F[Ntot] = nnz;
    }
}

__global__ __launch_bounds__(1024) void k_scan3(int* __restrict__ F, const int* __restrict__ bsum,
                                                int n, int* __restrict__ cur) {
    int i = blockIdx.x * 1024 + threadIdx.x;
    if (i < n) { int v = F[i] + bsum[blockIdx.x]; F[i] = v; cur[i] = v; }
}

// scatter (col,val) pairs fused into one int2 stream
__global__ void k_scatter(const int* __restrict__ rows, const int* __restrict__ cols,
                          const float* __restrict__ vals, int nnz,
                          int* __restrict__ cur, int2* __restrict__ sedge) {
    int i = blockIdx.x * blockDim.x + threadIdx.x;
    if (i < nnz) {
        int pos = atomicAdd(&cur[rows[i]], 1);
        int2 e; e.x = cols[i]; e.y = __float_as_int(vals[i]);
        sedge[pos] = e;
    }
}

// ---------------- SpMM gather: one wave per row, 8 edges in flight ----------------
template <int MODE>
__global__ __launch_bounds__(256) void k_spmm(
    const float* __restrict__ in, float* __restrict__ out, float* __restrict__ osum,
    const int* __restrict__ rs, const int2* __restrict__ sedge, int Ntot)
{
    const int r = blockIdx.x * 4 + (threadIdx.x >> 6);
    if (r >= Ntot) return;
    const int lane = threadIdx.x & 63;
    const int g = lane >> 4, q = lane & 15;
    const int e0 = rs[r], e1 = rs[r + 1];

    float4 acc = make_float4(0.f, 0.f, 0.f, 0.f);
    float4 acc2 = make_float4(0.f, 0.f, 0.f, 0.f);
    for (int eb = e0; eb < e1; eb += 8) {
        const int ea = eb + g, ebb = eb + 4 + g;
        if (ea < e1) {
            const int2 ed = sedge[ea];
            const float v = __int_as_float(ed.y);
            const float4 x = *(const float4*)(in + (((size_t)ed.x) << 6) + q * 4);
            acc.x += v * x.x; acc.y += v * x.y; acc.z += v * x.z; acc.w += v * x.w;
        }
        if (ebb < e1) {
            const int2 ed = sedge[ebb];
            const float v = __int_as_float(ed.y);
            const float4 x = *(const float4*)(in + (((size_t)ed.x) << 6) + q * 4);
            acc2.x += v * x.x; acc2.y += v * x.y; acc2.z += v * x.z; acc2.w += v * x.w;
        }
    }
    acc.x += acc2.x; acc.y += acc2.y; acc.z += acc2.z; acc.w += acc2.w;

    #pragma unroll
    for (int off = 16; off < 64; off <<= 1) {
        acc.x += __shfl_xor(acc.x, off, 64);
        acc.y += __shfl_xor(acc.y, off, 64);
        acc.z += __shfl_xor(acc.z, off, 64);
        acc.w += __shfl_xor(acc.w, off, 64);
    }

    if (g == 0) {
        const size_t oi = (((size_t)r) << 6) + q * 4;
        *(float4*)(out + oi) = acc;
        if (MODE == 0) {
            *(float4*)(osum + oi) = acc;
        } else {
            float4 s = *(const float4*)(osum + oi);
            s.x += acc.x; s.y += acc.y; s.z += acc.z; s.w += acc.w;
            *(float4*)(osum + oi) = s;
        }
    }
}

// ---------------- expmap0(out_sum, project=True) ----------------
__global__ void k_expmap_proj(const float* __restrict__ in, float* __restrict__ out, int Ntot) {
    const int w = threadIdx.x >> 6, d = threadIdx.x & 63;
    const int n = blockIdx.x * 4 + w;
    if (n >= Ntot) return;
    const float v = in[((size_t)n << 6) + d];
    const float ss = wsum(d == 0 ? 0.f : v * v);
    const float nr = fmaxf(sqrtf(ss), EPSF);
    const float r = sinhf(nr) / nr;
    const float sn = r * sqrtf(ss);
    const float scale = fminf(1.0f, MAXNRM / fmaxf(sn, EPSF));
    const float mult = r * scale;
    out[((size_t)n << 6) + d] = (d == 0) ? sqrtf(1.0f + mult * mult * ss) : mult * v;
}

// ---------------- triple margin loss: 16 lanes/triple, float4, block-reduced ----------------
__global__ __launch_bounds__(256) void k_triples(
    const float* __restrict__ O, const int* __restrict__ tri,
    int T, float* __restrict__ slot)
{
    const int lane = threadIdx.x & 63;
    const int g = lane >> 4, q = lane & 15;
    const int wid = blockIdx.x * 4 + (threadIdx.x >> 6);
    const int nwaves = gridDim.x * 4;

    float racc = 0.f;
    for (int tb = wid * 4; tb < T; tb += nwaves * 4) {
        const int t = tb + g;
        const int a = tri[3 * t], p = tri[3 * t + 1], nn = tri[3 * t + 2];
        const float4 av = *(const float4*)(O + (((size_t)a) << 6) + q * 4);
        const float4 pv = *(const float4*)(O + (((size_t)p) << 6) + q * 4);
        const float4 nv = *(const float4*)(O + (((size_t)nn) << 6) + q * 4);
        const float s0 = (q == 0) ? -1.f : 1.f;
        float i1 = s0 * av.x * pv.x + av.y * pv.y + av.z * pv.z + av.w * pv.w;
        float i2 = s0 * av.x * nv.x + av.y * nv.y + av.z * nv.z + av.w * nv.w;
        #pragma unroll
        for (int off = 1; off < 16; off <<= 1) {
            i1 += __shfl_xor(i1, off, 64);
            i2 += __shfl_xor(i2, off, 64);
        }
        if (q == 0) {
            const float d1 = acoshf(fmaxf(-i1, 1.0f + EPSF));
            const float d2 = acoshf(fmaxf(-i2, 1.0f + EPSF));
            const float l = d1 * d1 - d2 * d2 + 0.1f;
            if (l > 0.f) racc += l;
        }
    }

    racc = wsum(racc);
    __shared__ float sb[4];
    if (lane == 0) sb[threadIdx.x >> 6] = racc;
    __syncthreads();
    if (threadIdx.x == 0)
        atomicAdd(&slot[blockIdx.x & 255], sb[0] + sb[1] + sb[2] + sb[3]);
}

// ---------------- finalize ----------------
__global__ void k_final(const float* __restrict__ slots, float* __restrict__ out, int Ntot)
{
    const int tid = threadIdx.x;
    float m = slots[tid], r = slots[256 + tid], k = slots[512 + tid];
    m = wsum(m); r = wsum(r); k = wsum(k);
    __shared__ float sm[4], sr[4], sk[4];
    if ((tid & 63) == 0) { sm[tid >> 6] = m; sr[tid >> 6] = r; sk[tid >> 6] = k; }
    __syncthreads();
    if (tid == 0) {
        const float M = sm[0] + sm[1] + sm[2] + sm[3];
        const float R = sr[0] + sr[1] + sr[2] + sr[3];
        const float K = sk[0] + sk[1] + sk[2] + sk[3];
        const float recon = R / (float)Ntot;
        const float kl = -0.5f * K / ((float)Ntot * 64.0f);
        out[0] = M + 0.1f * (recon + kl);
    }
}

extern "C" void kernel_launch(void* const* d_in, const int* in_sizes, int n_in,
                              void* d_out, int out_size, void* d_ws, size_t ws_size,
                              hipStream_t stream)
{
    const float* emb_user = (const float*)d_in[0];
    const float* emb_item = (const float*)d_in[1];
    const int*   adj_rows = (const int*)d_in[2];
    const int*   adj_cols = (const int*)d_in[3];
    const float* adj_vals = (const float*)d_in[4];
    const int*   triples  = (const int*)d_in[5];
    const float* epsin    = (const float*)d_in[6];
    const float* tW  = (const float*)d_in[7];
    const float* tb  = (const float*)d_in[8];
    const float* tgW = (const float*)d_in[9];
    const float* tgb = (const float*)d_in[10];
    const float* muW = (const float*)d_in[11];
    const float* mub = (const float*)d_in[12];
    const float* lvW = (const float*)d_in[13];
    const float* lvb = (const float*)d_in[14];
    const float* f1W = (const float*)d_in[15];
    const float* f1b = (const float*)d_in[16];
    const float* f2W = (const float*)d_in[17];
    const float* f2b = (const float*)d_in[18];
    const float* dW  = (const float*)d_in[19];
    const float* db  = (const float*)d_in[20];
    const float* dgW = (const float*)d_in[21];
    const float* dgb = (const float*)d_in[22];

    const int Nu = in_sizes[0] / 64, Ni = in_sizes[1] / 64;
    const int N = Nu + Ni;            // 100000
    const int NNZ = in_sizes[4];      // 3200000
    const int T = in_sizes[5] / 3;    // 262144

    float* ws = (float*)d_ws;
    size_t off = 0;
    float* slots = ws + off; off += 1024;            // [0..256) margin, [256..512) recon, [512..768) kl
    float* A  = ws + off; off += (size_t)N * 64;     // t / h / h2 ; later overlaid with CSR edges
    float* B  = ws + off; off += (size_t)N * 64;     // m
    float* C  = ws + off; off += (size_t)N * 64;     // hm, then out_sum
    float* Dd = ws + off; off += (size_t)N * 64;     // spmm ping
    float* Ee = ws + off; off += (size_t)N * 64;     // spmm pong, then out
    int*   F  = (int*)(ws + off); off += (size_t)N + 64;   // row_start (N+1)
    int*   G  = (int*)(ws + off); off += (size_t)N;        // counts / cursor
    int*   bsum = (int*)(ws + off); off += 1024;

    // CSR edge storage overlays A (A dead after second k_moe, which precedes k_scatter)
    int2* sedge = (int2*)A;            // (col, val) pairs [NNZ] = 25.6 MB = N*64*4 bytes

    hipMemsetAsync(slots, 0, 1024 * sizeof(float), stream);
    hipMemsetAsync(G, 0, (size_t)N * sizeof(int), stream);

    const int nb32 = N / 32;          // 3125
    const int nbN4 = (N + 3) / 4;     // 25000

    k_logmap<<<(N * 64 + 255) / 256, 256, 0, stream>>>(emb_user, emb_item, Nu, N, A);
    k_moe<<<nb32, 256, 0, stream>>>(A, B, tW, tb, tgW, tgb);
    k_vae<<<nb32, 256, 0, stream>>>(B, A, epsin, muW, mub, lvW, lvb, slots + 512);
    k_ffn<<<nb32, 256, 0, stream>>>(A, f1W, f1b, f2W, f2b);
    k_moe<<<nb32, 256, 0, stream>>>(A, C, dW, db, dgW, dgb);
    k_recon<<<nbN4, 256, 0, stream>>>(C, B, N, slots + 256);

    k_count<<<(NNZ + 255) / 256, 256, 0, stream>>>(adj_rows, NNZ, G);
    const int nsb = (N + 1023) / 1024;   // 98
    k_scan1<<<nsb, 1024, 0, stream>>>(G, N, F, bsum);
    k_scan2<<<1, 64, 0, stream>>>(bsum, nsb, F, N, NNZ);
    k_scan3<<<nsb, 1024, 0, stream>>>(F, bsum, N, G);
    k_scatter<<<(NNZ + 255) / 256, 256, 0, stream>>>(adj_rows, adj_cols, adj_vals, NNZ, G, sedge);

    k_spmm<0><<<nbN4, 256, 0, stream>>>(B,  Dd, C, F, sedge, N);
    k_spmm<1><<<nbN4, 256, 0, stream>>>(Dd, Ee, C, F, sedge, N);
    k_spmm<1><<<nbN4, 256, 0, stream>>>(Ee, Dd, C, F, sedge, N);

    k_expmap_proj<<<nbN4, 256, 0, stream>>>(C, Ee, N);
    k_triples<<<2048, 256, 0, stream>>>(Ee, triples, T, slots);
    k_final<<<1, 256, 0, stream>>>(slots, (float*)d_out, N);
}